// Round 3
// baseline (340.145 us; speedup 1.0000x reference)
//
#include <hip/hip_runtime.h>
#include <stdint.h>

#define Bsz 2
#define Tseq 2048
#define Dmodel 1024
#define Hn 16
#define DKd 64

typedef __bf16 bf16;
typedef bf16 bf16x8 __attribute__((ext_vector_type(8)));
typedef float f32x4 __attribute__((ext_vector_type(4)));

// async global->LDS, 16B per lane. LDS dest must be wave-uniform base + lane*16
// and contiguous across the wave's lanes (no padding on DMA'd tiles).
__device__ inline void gld_lds16(const void* g, void* l) {
  __builtin_amdgcn_global_load_lds(
      (const __attribute__((address_space(1))) uint32_t*)g,
      (__attribute__((address_space(3))) uint32_t*)l, 16, 0, 0);
}

// pack 4 fp32 -> 4 bf16, single 8B store
__device__ inline void pack4_store(bf16* dst, float a, float b, float c, float d) {
  union { bf16 h[4]; uint2 u; } pk;
  pk.h[0] = (bf16)a; pk.h[1] = (bf16)b; pk.h[2] = (bf16)c; pk.h[3] = (bf16)d;
  *(uint2*)dst = pk.u;
}

// ---------------- fp32 -> bf16 convert (activations + weights) ----------------
struct CvtArgs {
  const float* src[7];
  bf16* dst[7];
  int n4[7];
};

__global__ void __launch_bounds__(256) cvt_f32_bf16(CvtArgs a) {
  const int z = blockIdx.y;
  const float4* s = (const float4*)a.src[z];
  uint2* d = (uint2*)a.dst[z];
  const int n4 = a.n4[z];
  for (int i = blockIdx.x * 256 + threadIdx.x; i < n4; i += gridDim.x * 256) {
    float4 v = s[i];
    union { bf16 h[4]; uint2 u; } pk;
    pk.h[0] = (bf16)v.x; pk.h[1] = (bf16)v.y;
    pk.h[2] = (bf16)v.z; pk.h[3] = (bf16)v.w;
    d[i] = pk.u;
  }
}

// ---------------- QKV GEMM: C = (A * W^T + bias)*scale, bf16 in --------------
// 128x128 tile, BK=32, XCD-swizzled 1D grid. T3 minimum-2-phase double buffer:
// stage(next K-tile) issued BEFORE compute(cur); the __syncthreads() drain at
// iteration end waits on loads issued one full compute phase earlier.
// LDS 32 KB (2x dbuf), 768 blocks -> 3 blocks/CU.
// mode 0: bf16 [B,H,T,DK]; mode 1: bf16 [B,H,DK,T].
struct GemmArgs {
  const bf16* A[3];
  const bf16* W[3];
  const float* bias[3];
  void* out[3];
  int mode[3];
  float scale[3];
};

__global__ void __launch_bounds__(256) gemm_qkv(GemmArgs g) {
  const int l = blockIdx.x;
  const int z = l >> 8;           // 768 = 3 * 256
  const int r = l & 255;
  const int mt = (r & 7) * 4 + (r >> 6);  // [0,32)
  const int nt = (r >> 3) & 7;            // [0,8)
  const bf16* __restrict__ A = g.A[z];
  const bf16* __restrict__ W = g.W[z];
  const float* __restrict__ bias = g.bias[z];
  const int mode = g.mode[z];
  const float scl = g.scale[z];

  __shared__ __align__(16) bf16 As[2][128 * 32];
  __shared__ __align__(16) bf16 Bs[2][128 * 32];

  const int tid = threadIdx.x;
  const int w = tid >> 6, lane = tid & 63;
  const int l15 = lane & 15, quad = lane >> 4;
  const int wm = (w >> 1) * 64, wn = (w & 1) * 64;
  const int m0 = mt * 128, n0 = nt * 128;

  // per-thread staging coords (2 chunks per buffer side)
  const int c0 = tid, c1 = 256 + tid;
  const int row0 = c0 >> 2, ko0 = (c0 & 3) * 8;
  const int row1 = c1 >> 2, ko1 = (c1 & 3) * 8;

  auto STAGE = [&](int buf, int k0) {
    gld_lds16(A + (size_t)(m0 + row0) * Dmodel + k0 + ko0, (void*)(As[buf] + c0 * 8));
    gld_lds16(W + (size_t)(n0 + row0) * Dmodel + k0 + ko0, (void*)(Bs[buf] + c0 * 8));
    gld_lds16(A + (size_t)(m0 + row1) * Dmodel + k0 + ko1, (void*)(As[buf] + c1 * 8));
    gld_lds16(W + (size_t)(n0 + row1) * Dmodel + k0 + ko1, (void*)(Bs[buf] + c1 * 8));
  };

  f32x4 zero = {0.f, 0.f, 0.f, 0.f};
  f32x4 acc[4][4];
#pragma unroll
  for (int mi = 0; mi < 4; ++mi)
#pragma unroll
    for (int ni = 0; ni < 4; ++ni) acc[mi][ni] = zero;

  STAGE(0, 0);
  __syncthreads();

  for (int t = 0; t < 32; ++t) {
    const int cur = t & 1;
    if (t < 31) STAGE(cur ^ 1, (t + 1) * 32);  // prefetch next K-tile

    bf16x8 af[4], bfr[4];
#pragma unroll
    for (int i = 0; i < 4; ++i) {
      af[i]  = *(const bf16x8*)(As[cur] + (wm + i * 16 + l15) * 32 + quad * 8);
      bfr[i] = *(const bf16x8*)(Bs[cur] + (wn + i * 16 + l15) * 32 + quad * 8);
    }
#pragma unroll
    for (int mi = 0; mi < 4; ++mi)
#pragma unroll
      for (int ni = 0; ni < 4; ++ni)
        acc[mi][ni] = __builtin_amdgcn_mfma_f32_16x16x32_bf16(af[mi], bfr[ni],
                                                              acc[mi][ni], 0, 0, 0);
    __syncthreads();  // drains vmcnt(0): next buffer landed; all reads done
  }

#pragma unroll
  for (int mi = 0; mi < 4; ++mi) {
#pragma unroll
    for (int r2 = 0; r2 < 4; ++r2) {
      const int m = m0 + wm + mi * 16 + quad * 4 + r2;
      const int bb = m >> 11, tt = m & 2047;
#pragma unroll
      for (int ni = 0; ni < 4; ++ni) {
        const int n = n0 + wn + ni * 16 + l15;
        const float val = (acc[mi][ni][r2] + bias[n]) * scl;
        bf16* o = (bf16*)g.out[z];
        const int hh = n >> 6, dk = n & 63;
        if (mode == 0) {
          o[((size_t)(bb * Hn + hh) * Tseq + tt) * DKd + dk] = (bf16)val;
        } else {
          o[((size_t)(bb * Hn + hh) * DKd + dk) * Tseq + tt] = (bf16)val;
        }
      }
    }
  }
}

// ---------------- out-projection GEMM, 64x128 tile, BK=32, dbuf 2-phase ------
__global__ void __launch_bounds__(256) gemm_out64(const bf16* __restrict__ A,
                                                  const bf16* __restrict__ W,
                                                  const float* __restrict__ bias,
                                                  float* __restrict__ out) {
  const int l = blockIdx.x;                // 512 blocks
  const int mt = (l & 7) * 8 + (l >> 6);   // [0,64)
  const int nt = (l >> 3) & 7;             // [0,8)

  __shared__ __align__(16) bf16 As[2][64 * 32];
  __shared__ __align__(16) bf16 Bs[2][128 * 32];

  const int tid = threadIdx.x;
  const int w = tid >> 6, lane = tid & 63;
  const int l15 = lane & 15, quad = lane >> 4;
  const int wm = (w >> 1) * 32, wn = (w & 1) * 64;
  const int m0 = mt * 64, n0 = nt * 128;

  const int c0 = tid, c1 = 256 + tid;
  const int rowA = c0 >> 2, koA = (c0 & 3) * 8;
  const int row0 = c0 >> 2, ko0 = (c0 & 3) * 8;
  const int row1 = c1 >> 2, ko1 = (c1 & 3) * 8;

  auto STAGE = [&](int buf, int k0) {
    gld_lds16(A + (size_t)(m0 + rowA) * Dmodel + k0 + koA, (void*)(As[buf] + c0 * 8));
    gld_lds16(W + (size_t)(n0 + row0) * Dmodel + k0 + ko0, (void*)(Bs[buf] + c0 * 8));
    gld_lds16(W + (size_t)(n0 + row1) * Dmodel + k0 + ko1, (void*)(Bs[buf] + c1 * 8));
  };

  f32x4 zero = {0.f, 0.f, 0.f, 0.f};
  f32x4 acc[2][4];
#pragma unroll
  for (int mi = 0; mi < 2; ++mi)
#pragma unroll
    for (int ni = 0; ni < 4; ++ni) acc[mi][ni] = zero;

  STAGE(0, 0);
  __syncthreads();

  for (int t = 0; t < 32; ++t) {
    const int cur = t & 1;
    if (t < 31) STAGE(cur ^ 1, (t + 1) * 32);

    bf16x8 af[2], bfr[4];
#pragma unroll
    for (int i = 0; i < 2; ++i)
      af[i] = *(const bf16x8*)(As[cur] + (wm + i * 16 + l15) * 32 + quad * 8);
#pragma unroll
    for (int i = 0; i < 4; ++i)
      bfr[i] = *(const bf16x8*)(Bs[cur] + (wn + i * 16 + l15) * 32 + quad * 8);
#pragma unroll
    for (int mi = 0; mi < 2; ++mi)
#pragma unroll
      for (int ni = 0; ni < 4; ++ni)
        acc[mi][ni] = __builtin_amdgcn_mfma_f32_16x16x32_bf16(af[mi], bfr[ni],
                                                              acc[mi][ni], 0, 0, 0);
    __syncthreads();
  }

#pragma unroll
  for (int mi = 0; mi < 2; ++mi)
#pragma unroll
    for (int r = 0; r < 4; ++r) {
      const int m = m0 + wm + mi * 16 + quad * 4 + r;
#pragma unroll
      for (int ni = 0; ni < 4; ++ni) {
        const int n = n0 + wn + ni * 16 + l15;
        out[(size_t)m * Dmodel + n] = acc[mi][ni][r] + bias[n];
      }
    }
}

// ---------------- fused causal attention (transposed-S, r7 tiling) -----------
// Round-3: T3 2-phase for the K/V pipeline.
//  * V staging removed (common-mistake #7): V fragments are loaded directly
//    global->VGPR per wave; all 32 q-blocks of one (b,h) land on one XCD
//    (grid stride 32 = 0 mod 8), so the 256 KB V panel is L2-resident.
//  * K LDS double-buffered in the freed 16 KB: per tile, V-loads issue first,
//    then next-tile K-DMA, then compute. PV's vmcnt wait on V leaves the K
//    DMAs in flight; the loop-top __syncthreads drain waits on DMAs issued a
//    full tile of compute earlier.
// LDS 2x16 + 17.4 = 49.4 KB -> 3 blocks/CU unchanged.
__global__ void __launch_bounds__(256) attn_fused(const bf16* __restrict__ Q,
                                                  const bf16* __restrict__ K,
                                                  const bf16* __restrict__ Vt,
                                                  bf16* __restrict__ ctx) {
  __shared__ __align__(16) bf16 Ks[2][8 * 128 * 8];  // dbuf [kc][row][8] 32 KB
  __shared__ __align__(16) bf16 plds[4][16][136];    // per-wave P [qrow][key] 17.4 KB

  const int tid = threadIdx.x;
  const int w = tid >> 6, lane = tid & 63;
  const int l15 = lane & 15, quad = lane >> 4;

  // longest-first: qt descending outer, (h,b) inner (stride 32 -> same XCD)
  const int l = blockIdx.x;                 // 1024 blocks
  const int qt = (Tseq / 64 - 1) - (l >> 5);
  const int hb = l & 31;
  const int h = hb & 15, b = hb >> 4;
  const int bh = b * Hn + h;
  const int qb = qt * 64 + w * 16;

  const bf16* Qb = Q + (size_t)bh * Tseq * DKd;
  const bf16* Kb = K + (size_t)bh * Tseq * DKd;
  const bf16* Vb = Vt + (size_t)bh * DKd * Tseq;

  auto STAGE_K = [&](int buf, int j0n) {
#pragma unroll
    for (int p = 0; p < 4; ++p) {
      const int c = p * 256 + tid;
      gld_lds16(Kb + (size_t)(j0n + (c & 127)) * DKd + (c >> 7) * 8,
                (void*)(Ks[buf] + c * 8));
    }
  };

  // Q fragment, B-operand role: n=l15 -> q-row, k=quad*8+j -> dk
  bf16x8 aq0 = *(const bf16x8*)(Qb + (size_t)(qb + l15) * DKd + quad * 8);
  bf16x8 aq1 = *(const bf16x8*)(Qb + (size_t)(qb + l15) * DKd + 32 + quad * 8);

  f32x4 zero = {0.f, 0.f, 0.f, 0.f};
  f32x4 oacc[4];
#pragma unroll
  for (int nd = 0; nd < 4; ++nd) oacc[nd] = zero;
  f32x4 lacc = zero;

  bf16x8 onesf;
#pragma unroll
  for (int i = 0; i < 8; ++i) onesf[i] = (bf16)1.0f;

  const int qmax = qt * 64 + 48;
  STAGE_K(0, 0);
  int cur = 0;

  for (int j0 = 0; j0 <= qmax; j0 += 128) {
    __syncthreads();  // Ks[cur] DMA landed (vmcnt drain); prev reads done

    // V fragments for this tile: direct global->VGPR (L2-resident panel).
    // A-operand role: row d = nd*16+l15, keys kc*32 + quad*8 + j.
    bf16x8 vf[4][4];
    const bool live = (j0 <= qb);
    if (live) {
#pragma unroll
      for (int kc = 0; kc < 4; ++kc)
#pragma unroll
        for (int nd = 0; nd < 4; ++nd)
          vf[kc][nd] = *(const bf16x8*)(Vb + (size_t)(nd * 16 + l15) * Tseq +
                                        j0 + kc * 32 + quad * 8);
    }

    // prefetch next K tile into the other buffer (DMA stays in flight
    // across this tile's compute; drained by next loop-top sync)
    if (j0 + 128 <= qmax) STAGE_K(cur ^ 1, j0 + 128);

    if (j0 + 128 <= qb) {
      // ---------- fully unmasked tile ----------
      f32x4 s[8];
#pragma unroll
      for (int ct = 0; ct < 8; ++ct) s[ct] = zero;
#pragma unroll
      for (int ct = 0; ct < 8; ++ct) {
        bf16x8 bk0 = *(const bf16x8*)(Ks[cur] + ((quad)*128 + ct * 16 + l15) * 8);
        bf16x8 bk1 = *(const bf16x8*)(Ks[cur] + ((4 + quad) * 128 + ct * 16 + l15) * 8);
        s[ct] = __builtin_amdgcn_mfma_f32_16x16x32_bf16(bk0, aq0, s[ct], 0, 0, 0);
        s[ct] = __builtin_amdgcn_mfma_f32_16x16x32_bf16(bk1, aq1, s[ct], 0, 0, 0);
      }
#pragma unroll
      for (int ct = 0; ct < 8; ++ct)
        pack4_store(&plds[w][l15][ct * 16 + quad * 4],
                    exp2f(s[ct][0]), exp2f(s[ct][1]),
                    exp2f(s[ct][2]), exp2f(s[ct][3]));
#pragma unroll
      for (int kc = 0; kc < 4; ++kc) {
        bf16x8 bp = *(const bf16x8*)(&plds[w][l15][kc * 32 + quad * 8]);
        lacc = __builtin_amdgcn_mfma_f32_16x16x32_bf16(onesf, bp, lacc, 0, 0, 0);
#pragma unroll
        for (int nd = 0; nd < 4; ++nd)
          oacc[nd] = __builtin_amdgcn_mfma_f32_16x16x32_bf16(vf[kc][nd], bp,
                                                             oacc[nd], 0, 0, 0);
      }
    } else if (live) {
      // ---------- diagonal tile: only live column-tiles (wave-uniform) -------
      const int ctl = ((qb - j0) >> 4) + 1;     // 1..8 live 16-col tiles
      const int kclim = (ctl + 1) >> 1;         // live 32-col PV chunks
      for (int ct = 0; ct < ctl; ++ct) {
        bf16x8 bk0 = *(const bf16x8*)(Ks[cur] + ((quad)*128 + ct * 16 + l15) * 8);
        bf16x8 bk1 = *(const bf16x8*)(Ks[cur] + ((4 + quad) * 128 + ct * 16 + l15) * 8);
        f32x4 s = zero;
        s = __builtin_amdgcn_mfma_f32_16x16x32_bf16(bk0, aq0, s, 0, 0, 0);
        s = __builtin_amdgcn_mfma_f32_16x16x32_bf16(bk1, aq1, s, 0, 0, 0);
        float p[4];
#pragma unroll
        for (int r = 0; r < 4; ++r) {
          p[r] = exp2f(s[r]);
          // mask only possible in the last live tile: key > qrow
          if (ct == ctl - 1 && (j0 + ct * 16 + quad * 4 + r > qb + l15)) p[r] = 0.f;
        }
        pack4_store(&plds[w][l15][ct * 16 + quad * 4], p[0], p[1], p[2], p[3]);
      }
      if (ctl < 8)  // zero the 16-col block the last b128 P-read may touch
        pack4_store(&plds[w][l15][ctl * 16 + quad * 4], 0.f, 0.f, 0.f, 0.f);
      for (int kc = 0; kc < kclim; ++kc) {
        bf16x8 bp = *(const bf16x8*)(&plds[w][l15][kc * 32 + quad * 8]);
        lacc = __builtin_amdgcn_mfma_f32_16x16x32_bf16(onesf, bp, lacc, 0, 0, 0);
#pragma unroll
        for (int nd = 0; nd < 4; ++nd)
          oacc[nd] = __builtin_amdgcn_mfma_f32_16x16x32_bf16(vf[kc][nd], bp,
                                                             oacc[nd], 0, 0, 0);
      }
    }
    cur ^= 1;
  }

  // epilogue: O^T lane layout = q-row l15, d = quad*4 + r (packed b64 stores)
  const float inv = 1.0f / lacc[0];
  bf16* cb = ctx + (size_t)(b * Tseq + qb + l15) * Dmodel + h * DKd + quad * 4;
#pragma unroll
  for (int nd = 0; nd < 4; ++nd)
    pack4_store(cb + nd * 16, oacc[nd][0] * inv, oacc[nd][1] * inv,
                oacc[nd][2] * inv, oacc[nd][3] * inv);
}

// -------------------------------- launcher ------------------------------------
extern "C" void kernel_launch(void* const* d_in, const int* in_sizes, int n_in,
                              void* d_out, int out_size, void* d_ws, size_t ws_size,
                              hipStream_t stream) {
  const float* q = (const float*)d_in[0];
  const float* k = (const float*)d_in[1];
  const float* v = (const float*)d_in[2];
  // d_in[3] = attn_mask (causal, known statically) - unused
  const float* Wq = (const float*)d_in[4];
  const float* bq = (const float*)d_in[5];
  const float* Wk = (const float*)d_in[6];
  const float* bk = (const float*)d_in[7];
  const float* Wv = (const float*)d_in[8];
  const float* bv = (const float*)d_in[9];
  const float* Wo = (const float*)d_in[10];
  const float* bo = (const float*)d_in[11];

  char* ws = (char*)d_ws;
  const size_t MB = 1024 * 1024;
  bf16* Wq_b = (bf16*)(ws + 0 * MB);
  bf16* Wk_b = (bf16*)(ws + 2 * MB);
  bf16* Wv_b = (bf16*)(ws + 4 * MB);
  bf16* Wo_b = (bf16*)(ws + 6 * MB);
  bf16* q_b  = (bf16*)(ws + 8 * MB);   // dead after QKV gemm
  bf16* k_b  = (bf16*)(ws + 16 * MB);
  bf16* v_b  = (bf16*)(ws + 24 * MB);
  bf16* Qh   = (bf16*)(ws + 32 * MB);  // [B,H,T,DK], pre-scaled
  bf16* Kh   = (bf16*)(ws + 40 * MB);  // [B,H,T,DK]
  bf16* Vt   = (bf16*)(ws + 48 * MB);  // [B,H,DK,T]
  bf16* ctx  = (bf16*)(ws + 8 * MB);   // aliases q_b (dead by then)

  const int NACT4 = (Bsz * Tseq * Dmodel) / 4;
  const int NW4 = (Dmodel * Dmodel) / 4;

  CvtArgs ca;
  ca.src[0] = q;  ca.dst[0] = q_b;  ca.n4[0] = NACT4;
  ca.src[1] = k;  ca.dst[1] = k_b;  ca.n4[1] = NACT4;
  ca.src[2] = v;  ca.dst[2] = v_b;  ca.n4[2] = NACT4;
  ca.src[3] = Wq; ca.dst[3] = Wq_b; ca.n4[3] = NW4;
  ca.src[4] = Wk; ca.dst[4] = Wk_b; ca.n4[4] = NW4;
  ca.src[5] = Wv; ca.dst[5] = Wv_b; ca.n4[5] = NW4;
  ca.src[6] = Wo; ca.dst[6] = Wo_b; ca.n4[6] = NW4;
  cvt_f32_bf16<<<dim3(512, 7), 256, 0, stream>>>(ca);

  const float SC = 0.125f * 1.4426950408889634f;  // 1/sqrt(DK) * log2(e)
  GemmArgs ga;
  ga.A[0] = q_b; ga.W[0] = Wq_b; ga.bias[0] = bq; ga.out[0] = Qh; ga.mode[0] = 0; ga.scale[0] = SC;
  ga.A[1] = k_b; ga.W[1] = Wk_b; ga.bias[1] = bk; ga.out[1] = Kh; ga.mode[1] = 0; ga.scale[1] = 1.f;
  ga.A[2] = v_b; ga.W[2] = Wv_b; ga.bias[2] = bv; ga.out[2] = Vt; ga.mode[2] = 1; ga.scale[2] = 1.f;
  gemm_qkv<<<dim3(768), 256, 0, stream>>>(ga);

  attn_fused<<<dim3((Tseq / 64) * Hn * Bsz), 256, 0, stream>>>(Qh, Kh, Vt, ctx);

  gemm_out64<<<dim3(512), 256, 0, stream>>>(ctx, Wo_b, bo, (float*)d_out);
}

// Round 4
// 277.991 us; speedup vs baseline: 1.2236x; 1.2236x over previous
//
#include <hip/hip_runtime.h>
#include <stdint.h>

#define Bsz 2
#define Tseq 2048
#define Dmodel 1024
#define Hn 16
#define DKd 64

typedef __bf16 bf16;
typedef bf16 bf16x8 __attribute__((ext_vector_type(8)));
typedef float f32x4 __attribute__((ext_vector_type(4)));

// async global->LDS, 16B per lane. LDS dest must be wave-uniform base + lane*16
// and contiguous across the wave's lanes (no padding on DMA'd tiles).
__device__ inline void gld_lds16(const void* g, void* l) {
  __builtin_amdgcn_global_load_lds(
      (const __attribute__((address_space(1))) uint32_t*)g,
      (__attribute__((address_space(3))) uint32_t*)l, 16, 0, 0);
}

// pack 4 fp32 -> 4 bf16, single 8B store
__device__ inline void pack4_store(bf16* dst, float a, float b, float c, float d) {
  union { bf16 h[4]; uint2 u; } pk;
  pk.h[0] = (bf16)a; pk.h[1] = (bf16)b; pk.h[2] = (bf16)c; pk.h[3] = (bf16)d;
  *(uint2*)dst = pk.u;
}

// ---------------- fp32 -> bf16 convert (activations + weights) ----------------
struct CvtArgs {
  const float* src[7];
  bf16* dst[7];
  int n4[7];
};

__global__ void __launch_bounds__(256) cvt_f32_bf16(CvtArgs a) {
  const int z = blockIdx.y;
  const float4* s = (const float4*)a.src[z];
  uint2* d = (uint2*)a.dst[z];
  const int n4 = a.n4[z];
  for (int i = blockIdx.x * 256 + threadIdx.x; i < n4; i += gridDim.x * 256) {
    float4 v = s[i];
    union { bf16 h[4]; uint2 u; } pk;
    pk.h[0] = (bf16)v.x; pk.h[1] = (bf16)v.y;
    pk.h[2] = (bf16)v.z; pk.h[3] = (bf16)v.w;
    d[i] = pk.u;
  }
}

// ---------------- QKV GEMM: C = (A * W^T + bias)*scale, bf16 in --------------
// 128x128 tile, BK=32, XCD-swizzled 1D grid. T3 minimum-2-phase double buffer:
// stage(next K-tile) issued BEFORE compute(cur); the __syncthreads() drain at
// iteration end waits on loads issued one full compute phase earlier.
// LDS 32 KB (2x dbuf), 768 blocks -> 3 blocks/CU.
// mode 0: bf16 [B,H,T,DK]; mode 1: bf16 [B,H,DK,T].
struct GemmArgs {
  const bf16* A[3];
  const bf16* W[3];
  const float* bias[3];
  void* out[3];
  int mode[3];
  float scale[3];
};

__global__ void __launch_bounds__(256) gemm_qkv(GemmArgs g) {
  const int l = blockIdx.x;
  const int z = l >> 8;           // 768 = 3 * 256
  const int r = l & 255;
  const int mt = (r & 7) * 4 + (r >> 6);  // [0,32)
  const int nt = (r >> 3) & 7;            // [0,8)
  const bf16* __restrict__ A = g.A[z];
  const bf16* __restrict__ W = g.W[z];
  const float* __restrict__ bias = g.bias[z];
  const int mode = g.mode[z];
  const float scl = g.scale[z];

  __shared__ __align__(16) bf16 As[2][128 * 32];
  __shared__ __align__(16) bf16 Bs[2][128 * 32];

  const int tid = threadIdx.x;
  const int w = tid >> 6, lane = tid & 63;
  const int l15 = lane & 15, quad = lane >> 4;
  const int wm = (w >> 1) * 64, wn = (w & 1) * 64;
  const int m0 = mt * 128, n0 = nt * 128;

  // per-thread staging coords (2 chunks per buffer side)
  const int c0 = tid, c1 = 256 + tid;
  const int row0 = c0 >> 2, ko0 = (c0 & 3) * 8;
  const int row1 = c1 >> 2, ko1 = (c1 & 3) * 8;

  auto STAGE = [&](int buf, int k0) {
    gld_lds16(A + (size_t)(m0 + row0) * Dmodel + k0 + ko0, (void*)(As[buf] + c0 * 8));
    gld_lds16(W + (size_t)(n0 + row0) * Dmodel + k0 + ko0, (void*)(Bs[buf] + c0 * 8));
    gld_lds16(A + (size_t)(m0 + row1) * Dmodel + k0 + ko1, (void*)(As[buf] + c1 * 8));
    gld_lds16(W + (size_t)(n0 + row1) * Dmodel + k0 + ko1, (void*)(Bs[buf] + c1 * 8));
  };

  f32x4 zero = {0.f, 0.f, 0.f, 0.f};
  f32x4 acc[4][4];
#pragma unroll
  for (int mi = 0; mi < 4; ++mi)
#pragma unroll
    for (int ni = 0; ni < 4; ++ni) acc[mi][ni] = zero;

  STAGE(0, 0);
  __syncthreads();

  for (int t = 0; t < 32; ++t) {
    const int cur = t & 1;
    if (t < 31) STAGE(cur ^ 1, (t + 1) * 32);  // prefetch next K-tile

    bf16x8 af[4], bfr[4];
#pragma unroll
    for (int i = 0; i < 4; ++i) {
      af[i]  = *(const bf16x8*)(As[cur] + (wm + i * 16 + l15) * 32 + quad * 8);
      bfr[i] = *(const bf16x8*)(Bs[cur] + (wn + i * 16 + l15) * 32 + quad * 8);
    }
#pragma unroll
    for (int mi = 0; mi < 4; ++mi)
#pragma unroll
      for (int ni = 0; ni < 4; ++ni)
        acc[mi][ni] = __builtin_amdgcn_mfma_f32_16x16x32_bf16(af[mi], bfr[ni],
                                                              acc[mi][ni], 0, 0, 0);
    __syncthreads();  // drains vmcnt(0): next buffer landed; all reads done
  }

#pragma unroll
  for (int mi = 0; mi < 4; ++mi) {
#pragma unroll
    for (int r2 = 0; r2 < 4; ++r2) {
      const int m = m0 + wm + mi * 16 + quad * 4 + r2;
      const int bb = m >> 11, tt = m & 2047;
#pragma unroll
      for (int ni = 0; ni < 4; ++ni) {
        const int n = n0 + wn + ni * 16 + l15;
        const float val = (acc[mi][ni][r2] + bias[n]) * scl;
        bf16* o = (bf16*)g.out[z];
        const int hh = n >> 6, dk = n & 63;
        if (mode == 0) {
          o[((size_t)(bb * Hn + hh) * Tseq + tt) * DKd + dk] = (bf16)val;
        } else {
          o[((size_t)(bb * Hn + hh) * DKd + dk) * Tseq + tt] = (bf16)val;
        }
      }
    }
  }
}

// ---------------- out-projection GEMM, 64x128 tile, BK=32, dbuf 2-phase ------
__global__ void __launch_bounds__(256) gemm_out64(const bf16* __restrict__ A,
                                                  const bf16* __restrict__ W,
                                                  const float* __restrict__ bias,
                                                  float* __restrict__ out) {
  const int l = blockIdx.x;                // 512 blocks
  const int mt = (l & 7) * 8 + (l >> 6);   // [0,64)
  const int nt = (l >> 3) & 7;             // [0,8)

  __shared__ __align__(16) bf16 As[2][64 * 32];
  __shared__ __align__(16) bf16 Bs[2][128 * 32];

  const int tid = threadIdx.x;
  const int w = tid >> 6, lane = tid & 63;
  const int l15 = lane & 15, quad = lane >> 4;
  const int wm = (w >> 1) * 32, wn = (w & 1) * 64;
  const int m0 = mt * 64, n0 = nt * 128;

  const int c0 = tid, c1 = 256 + tid;
  const int rowA = c0 >> 2, koA = (c0 & 3) * 8;
  const int row0 = c0 >> 2, ko0 = (c0 & 3) * 8;
  const int row1 = c1 >> 2, ko1 = (c1 & 3) * 8;

  auto STAGE = [&](int buf, int k0) {
    gld_lds16(A + (size_t)(m0 + rowA) * Dmodel + k0 + koA, (void*)(As[buf] + c0 * 8));
    gld_lds16(W + (size_t)(n0 + row0) * Dmodel + k0 + ko0, (void*)(Bs[buf] + c0 * 8));
    gld_lds16(W + (size_t)(n0 + row1) * Dmodel + k0 + ko1, (void*)(Bs[buf] + c1 * 8));
  };

  f32x4 zero = {0.f, 0.f, 0.f, 0.f};
  f32x4 acc[2][4];
#pragma unroll
  for (int mi = 0; mi < 2; ++mi)
#pragma unroll
    for (int ni = 0; ni < 4; ++ni) acc[mi][ni] = zero;

  STAGE(0, 0);
  __syncthreads();

  for (int t = 0; t < 32; ++t) {
    const int cur = t & 1;
    if (t < 31) STAGE(cur ^ 1, (t + 1) * 32);

    bf16x8 af[2], bfr[4];
#pragma unroll
    for (int i = 0; i < 2; ++i)
      af[i] = *(const bf16x8*)(As[cur] + (wm + i * 16 + l15) * 32 + quad * 8);
#pragma unroll
    for (int i = 0; i < 4; ++i)
      bfr[i] = *(const bf16x8*)(Bs[cur] + (wn + i * 16 + l15) * 32 + quad * 8);
#pragma unroll
    for (int mi = 0; mi < 2; ++mi)
#pragma unroll
      for (int ni = 0; ni < 4; ++ni)
        acc[mi][ni] = __builtin_amdgcn_mfma_f32_16x16x32_bf16(af[mi], bfr[ni],
                                                              acc[mi][ni], 0, 0, 0);
    __syncthreads();
  }

#pragma unroll
  for (int mi = 0; mi < 2; ++mi)
#pragma unroll
    for (int r = 0; r < 4; ++r) {
      const int m = m0 + wm + mi * 16 + quad * 4 + r;
#pragma unroll
      for (int ni = 0; ni < 4; ++ni) {
        const int n = n0 + wn + ni * 16 + l15;
        out[(size_t)m * Dmodel + n] = acc[mi][ni][r] + bias[n];
      }
    }
}

// ---------------- fused causal attention (transposed-S, r7 tiling) -----------
// Round-4: round-3 structure (direct-V to VGPR, K LDS dbuf) with the rule-#20
// fix: the diagonal PV loop is fully unrolled with a wave-uniform guard, so
// vf[][] is ALWAYS statically indexed and stays in VGPRs (round-3 spilled the
// whole array to scratch -> 520 MB of WRITE_SIZE).
// LDS 2x16 + 17.4 = 49.4 KB -> 3 blocks/CU.
__global__ void __launch_bounds__(256) attn_fused(const bf16* __restrict__ Q,
                                                  const bf16* __restrict__ K,
                                                  const bf16* __restrict__ Vt,
                                                  bf16* __restrict__ ctx) {
  __shared__ __align__(16) bf16 Ks[2][8 * 128 * 8];  // dbuf [kc][row][8] 32 KB
  __shared__ __align__(16) bf16 plds[4][16][136];    // per-wave P [qrow][key] 17.4 KB

  const int tid = threadIdx.x;
  const int w = tid >> 6, lane = tid & 63;
  const int l15 = lane & 15, quad = lane >> 4;

  // longest-first: qt descending outer, (h,b) inner (stride 32 -> same XCD)
  const int l = blockIdx.x;                 // 1024 blocks
  const int qt = (Tseq / 64 - 1) - (l >> 5);
  const int hb = l & 31;
  const int h = hb & 15, b = hb >> 4;
  const int bh = b * Hn + h;
  const int qb = qt * 64 + w * 16;

  const bf16* Qb = Q + (size_t)bh * Tseq * DKd;
  const bf16* Kb = K + (size_t)bh * Tseq * DKd;
  const bf16* Vb = Vt + (size_t)bh * DKd * Tseq;

  auto STAGE_K = [&](int buf, int j0n) {
#pragma unroll
    for (int p = 0; p < 4; ++p) {
      const int c = p * 256 + tid;
      gld_lds16(Kb + (size_t)(j0n + (c & 127)) * DKd + (c >> 7) * 8,
                (void*)(Ks[buf] + c * 8));
    }
  };

  // Q fragment, B-operand role: n=l15 -> q-row, k=quad*8+j -> dk
  bf16x8 aq0 = *(const bf16x8*)(Qb + (size_t)(qb + l15) * DKd + quad * 8);
  bf16x8 aq1 = *(const bf16x8*)(Qb + (size_t)(qb + l15) * DKd + 32 + quad * 8);

  f32x4 zero = {0.f, 0.f, 0.f, 0.f};
  f32x4 oacc[4];
#pragma unroll
  for (int nd = 0; nd < 4; ++nd) oacc[nd] = zero;
  f32x4 lacc = zero;

  bf16x8 onesf;
#pragma unroll
  for (int i = 0; i < 8; ++i) onesf[i] = (bf16)1.0f;

  const int qmax = qt * 64 + 48;
  STAGE_K(0, 0);
  int cur = 0;

  for (int j0 = 0; j0 <= qmax; j0 += 128) {
    __syncthreads();  // Ks[cur] DMA landed (vmcnt drain); prev reads done

    // V fragments for this tile: direct global->VGPR (L2-resident panel).
    // A-operand role: row d = nd*16+l15, keys kc*32 + quad*8 + j.
    bf16x8 vf[4][4];
    const bool live = (j0 <= qb);
    if (live) {
#pragma unroll
      for (int kc = 0; kc < 4; ++kc)
#pragma unroll
        for (int nd = 0; nd < 4; ++nd)
          vf[kc][nd] = *(const bf16x8*)(Vb + (size_t)(nd * 16 + l15) * Tseq +
                                        j0 + kc * 32 + quad * 8);
    }

    // prefetch next K tile into the other buffer (DMA stays in flight
    // across this tile's compute; drained by next loop-top sync)
    if (j0 + 128 <= qmax) STAGE_K(cur ^ 1, j0 + 128);

    if (j0 + 128 <= qb) {
      // ---------- fully unmasked tile ----------
      f32x4 s[8];
#pragma unroll
      for (int ct = 0; ct < 8; ++ct) s[ct] = zero;
#pragma unroll
      for (int ct = 0; ct < 8; ++ct) {
        bf16x8 bk0 = *(const bf16x8*)(Ks[cur] + ((quad)*128 + ct * 16 + l15) * 8);
        bf16x8 bk1 = *(const bf16x8*)(Ks[cur] + ((4 + quad) * 128 + ct * 16 + l15) * 8);
        s[ct] = __builtin_amdgcn_mfma_f32_16x16x32_bf16(bk0, aq0, s[ct], 0, 0, 0);
        s[ct] = __builtin_amdgcn_mfma_f32_16x16x32_bf16(bk1, aq1, s[ct], 0, 0, 0);
      }
#pragma unroll
      for (int ct = 0; ct < 8; ++ct)
        pack4_store(&plds[w][l15][ct * 16 + quad * 4],
                    exp2f(s[ct][0]), exp2f(s[ct][1]),
                    exp2f(s[ct][2]), exp2f(s[ct][3]));
#pragma unroll
      for (int kc = 0; kc < 4; ++kc) {
        bf16x8 bp = *(const bf16x8*)(&plds[w][l15][kc * 32 + quad * 8]);
        lacc = __builtin_amdgcn_mfma_f32_16x16x32_bf16(onesf, bp, lacc, 0, 0, 0);
#pragma unroll
        for (int nd = 0; nd < 4; ++nd)
          oacc[nd] = __builtin_amdgcn_mfma_f32_16x16x32_bf16(vf[kc][nd], bp,
                                                             oacc[nd], 0, 0, 0);
      }
    } else if (live) {
      // ---------- diagonal tile: only live column-tiles (wave-uniform) -------
      const int ctl = ((qb - j0) >> 4) + 1;     // 1..8 live 16-col tiles
      const int kclim = (ctl + 1) >> 1;         // live 32-col PV chunks
      for (int ct = 0; ct < ctl; ++ct) {
        bf16x8 bk0 = *(const bf16x8*)(Ks[cur] + ((quad)*128 + ct * 16 + l15) * 8);
        bf16x8 bk1 = *(const bf16x8*)(Ks[cur] + ((4 + quad) * 128 + ct * 16 + l15) * 8);
        f32x4 s = zero;
        s = __builtin_amdgcn_mfma_f32_16x16x32_bf16(bk0, aq0, s, 0, 0, 0);
        s = __builtin_amdgcn_mfma_f32_16x16x32_bf16(bk1, aq1, s, 0, 0, 0);
        float p[4];
#pragma unroll
        for (int r = 0; r < 4; ++r) {
          p[r] = exp2f(s[r]);
          // mask only possible in the last live tile: key > qrow
          if (ct == ctl - 1 && (j0 + ct * 16 + quad * 4 + r > qb + l15)) p[r] = 0.f;
        }
        pack4_store(&plds[w][l15][ct * 16 + quad * 4], p[0], p[1], p[2], p[3]);
      }
      if (ctl < 8)  // zero the 16-col block the last b128 P-read may touch
        pack4_store(&plds[w][l15][ctl * 16 + quad * 4], 0.f, 0.f, 0.f, 0.f);
      // rule-#20 fix: static kc indexing, wave-uniform guard per unrolled copy
#pragma unroll
      for (int kc = 0; kc < 4; ++kc) {
        if (kc < kclim) {
          bf16x8 bp = *(const bf16x8*)(&plds[w][l15][kc * 32 + quad * 8]);
          lacc = __builtin_amdgcn_mfma_f32_16x16x32_bf16(onesf, bp, lacc, 0, 0, 0);
#pragma unroll
          for (int nd = 0; nd < 4; ++nd)
            oacc[nd] = __builtin_amdgcn_mfma_f32_16x16x32_bf16(vf[kc][nd], bp,
                                                               oacc[nd], 0, 0, 0);
        }
      }
    }
    cur ^= 1;
  }

  // epilogue: O^T lane layout = q-row l15, d = quad*4 + r (packed b64 stores)
  const float inv = 1.0f / lacc[0];
  bf16* cb = ctx + (size_t)(b * Tseq + qb + l15) * Dmodel + h * DKd + quad * 4;
#pragma unroll
  for (int nd = 0; nd < 4; ++nd)
    pack4_store(cb + nd * 16, oacc[nd][0] * inv, oacc[nd][1] * inv,
                oacc[nd][2] * inv, oacc[nd][3] * inv);
}

// -------------------------------- launcher ------------------------------------
extern "C" void kernel_launch(void* const* d_in, const int* in_sizes, int n_in,
                              void* d_out, int out_size, void* d_ws, size_t ws_size,
                              hipStream_t stream) {
  const float* q = (const float*)d_in[0];
  const float* k = (const float*)d_in[1];
  const float* v = (const float*)d_in[2];
  // d_in[3] = attn_mask (causal, known statically) - unused
  const float* Wq = (const float*)d_in[4];
  const float* bq = (const float*)d_in[5];
  const float* Wk = (const float*)d_in[6];
  const float* bk = (const float*)d_in[7];
  const float* Wv = (const float*)d_in[8];
  const float* bv = (const float*)d_in[9];
  const float* Wo = (const float*)d_in[10];
  const float* bo = (const float*)d_in[11];

  char* ws = (char*)d_ws;
  const size_t MB = 1024 * 1024;
  bf16* Wq_b = (bf16*)(ws + 0 * MB);
  bf16* Wk_b = (bf16*)(ws + 2 * MB);
  bf16* Wv_b = (bf16*)(ws + 4 * MB);
  bf16* Wo_b = (bf16*)(ws + 6 * MB);
  bf16* q_b  = (bf16*)(ws + 8 * MB);   // dead after QKV gemm
  bf16* k_b  = (bf16*)(ws + 16 * MB);
  bf16* v_b  = (bf16*)(ws + 24 * MB);
  bf16* Qh   = (bf16*)(ws + 32 * MB);  // [B,H,T,DK], pre-scaled
  bf16* Kh   = (bf16*)(ws + 40 * MB);  // [B,H,T,DK]
  bf16* Vt   = (bf16*)(ws + 48 * MB);  // [B,H,DK,T]
  bf16* ctx  = (bf16*)(ws + 8 * MB);   // aliases q_b (dead by then)

  const int NACT4 = (Bsz * Tseq * Dmodel) / 4;
  const int NW4 = (Dmodel * Dmodel) / 4;

  CvtArgs ca;
  ca.src[0] = q;  ca.dst[0] = q_b;  ca.n4[0] = NACT4;
  ca.src[1] = k;  ca.dst[1] = k_b;  ca.n4[1] = NACT4;
  ca.src[2] = v;  ca.dst[2] = v_b;  ca.n4[2] = NACT4;
  ca.src[3] = Wq; ca.dst[3] = Wq_b; ca.n4[3] = NW4;
  ca.src[4] = Wk; ca.dst[4] = Wk_b; ca.n4[4] = NW4;
  ca.src[5] = Wv; ca.dst[5] = Wv_b; ca.n4[5] = NW4;
  ca.src[6] = Wo; ca.dst[6] = Wo_b; ca.n4[6] = NW4;
  cvt_f32_bf16<<<dim3(512, 7), 256, 0, stream>>>(ca);

  const float SC = 0.125f * 1.4426950408889634f;  // 1/sqrt(DK) * log2(e)
  GemmArgs ga;
  ga.A[0] = q_b; ga.W[0] = Wq_b; ga.bias[0] = bq; ga.out[0] = Qh; ga.mode[0] = 0; ga.scale[0] = SC;
  ga.A[1] = k_b; ga.W[1] = Wk_b; ga.bias[1] = bk; ga.out[1] = Kh; ga.mode[1] = 0; ga.scale[1] = 1.f;
  ga.A[2] = v_b; ga.W[2] = Wv_b; ga.bias[2] = bv; ga.out[2] = Vt; ga.mode[2] = 1; ga.scale[2] = 1.f;
  gemm_qkv<<<dim3(768), 256, 0, stream>>>(ga);

  attn_fused<<<dim3((Tseq / 64) * Hn * Bsz), 256, 0, stream>>>(Qh, Kh, Vt, ctx);

  gemm_out64<<<dim3(512), 256, 0, stream>>>(ctx, Wo_b, bo, (float*)d_out);
}

// Round 5
// 273.178 us; speedup vs baseline: 1.2451x; 1.0176x over previous
//
#include <hip/hip_runtime.h>
#include <stdint.h>

#define Bsz 2
#define Tseq 2048
#define Dmodel 1024
#define Hn 16
#define DKd 64

typedef __bf16 bf16;
typedef bf16 bf16x8 __attribute__((ext_vector_type(8)));
typedef float f32x4 __attribute__((ext_vector_type(4)));

// async global->LDS, 16B per lane. LDS dest must be wave-uniform base + lane*16
// and contiguous across the wave's lanes (no padding on DMA'd tiles).
__device__ inline void gld_lds16(const void* g, void* l) {
  __builtin_amdgcn_global_load_lds(
      (const __attribute__((address_space(1))) uint32_t*)g,
      (__attribute__((address_space(3))) uint32_t*)l, 16, 0, 0);
}

// pack 4 fp32 -> 4 bf16, single 8B store
__device__ inline void pack4_store(bf16* dst, float a, float b, float c, float d) {
  union { bf16 h[4]; uint2 u; } pk;
  pk.h[0] = (bf16)a; pk.h[1] = (bf16)b; pk.h[2] = (bf16)c; pk.h[3] = (bf16)d;
  *(uint2*)dst = pk.u;
}

// 8 fp32 (two float4) -> bf16x8
__device__ inline bf16x8 cvt8(float4 a, float4 b) {
  bf16x8 r;
  r[0] = (bf16)a.x; r[1] = (bf16)a.y; r[2] = (bf16)a.z; r[3] = (bf16)a.w;
  r[4] = (bf16)b.x; r[5] = (bf16)b.y; r[6] = (bf16)b.z; r[7] = (bf16)b.w;
  return r;
}

// ---------------- fp32 -> bf16 convert (weights only now) --------------------
struct CvtArgs {
  const float* src[4];
  bf16* dst[4];
  int n4[4];
};

__global__ void __launch_bounds__(256) cvt_f32_bf16(CvtArgs a) {
  const int z = blockIdx.y;
  const float4* s = (const float4*)a.src[z];
  uint2* d = (uint2*)a.dst[z];
  const int n4 = a.n4[z];
  for (int i = blockIdx.x * 256 + threadIdx.x; i < n4; i += gridDim.x * 256) {
    float4 v = s[i];
    union { bf16 h[4]; uint2 u; } pk;
    pk.h[0] = (bf16)v.x; pk.h[1] = (bf16)v.y;
    pk.h[2] = (bf16)v.z; pk.h[3] = (bf16)v.w;
    d[i] = pk.u;
  }
}

// ---------------- QKV GEMM: C = (A_f32 * W^T + bias)*scale -------------------
// 128x128 tile, BK=32, XCD-swizzled 1D grid, 2-phase dbuf. Round-5: the fp32
// activation convert is FUSED into staging: A is loaded global->reg (two named
// float4 sets, issue-early), converted, ds_written to the other buffer while
// compute runs on cur (T14). W stays bf16 gld_lds16 DMA. Saves the acts cvt
// pass (~75 MB of the 100 MB cvt traffic).
struct GemmArgs {
  const float* A[3];    // fp32 activations
  const bf16* W[3];     // bf16 weights (pre-converted)
  const float* bias[3];
  void* out[3];
  int mode[3];
  float scale[3];
};

__global__ void __launch_bounds__(256) gemm_qkv(GemmArgs g) {
  const int l = blockIdx.x;
  const int z = l >> 8;           // 768 = 3 * 256
  const int r = l & 255;
  const int mt = (r & 7) * 4 + (r >> 6);  // [0,32)
  const int nt = (r >> 3) & 7;            // [0,8)
  const float* __restrict__ A = g.A[z];
  const bf16* __restrict__ W = g.W[z];
  const float* __restrict__ bias = g.bias[z];
  const int mode = g.mode[z];
  const float scl = g.scale[z];

  __shared__ __align__(16) bf16 As[2][128 * 32];
  __shared__ __align__(16) bf16 Bs[2][128 * 32];

  const int tid = threadIdx.x;
  const int w = tid >> 6, lane = tid & 63;
  const int l15 = lane & 15, quad = lane >> 4;
  const int wm = (w >> 1) * 64, wn = (w & 1) * 64;
  const int m0 = mt * 128, n0 = nt * 128;

  const int c0 = tid, c1 = 256 + tid;
  const int row0 = c0 >> 2, ko0 = (c0 & 3) * 8;
  const int row1 = c1 >> 2, ko1 = (c1 & 3) * 8;
  const float* Ar0 = A + (size_t)(m0 + row0) * Dmodel + ko0;
  const float* Ar1 = A + (size_t)(m0 + row1) * Dmodel + ko1;

  float4 s0a, s0b, s0c, s0d, s1a, s1b, s1c, s1d;  // two named reg sets

  auto LOAD0 = [&](int kk) {
    s0a = *(const float4*)(Ar0 + kk); s0b = *(const float4*)(Ar0 + kk + 4);
    s0c = *(const float4*)(Ar1 + kk); s0d = *(const float4*)(Ar1 + kk + 4);
  };
  auto LOAD1 = [&](int kk) {
    s1a = *(const float4*)(Ar0 + kk); s1b = *(const float4*)(Ar0 + kk + 4);
    s1c = *(const float4*)(Ar1 + kk); s1d = *(const float4*)(Ar1 + kk + 4);
  };
  auto WRITE0 = [&](int buf) {
    *(bf16x8*)(As[buf] + c0 * 8) = cvt8(s0a, s0b);
    *(bf16x8*)(As[buf] + c1 * 8) = cvt8(s0c, s0d);
  };
  auto WRITE1 = [&](int buf) {
    *(bf16x8*)(As[buf] + c0 * 8) = cvt8(s1a, s1b);
    *(bf16x8*)(As[buf] + c1 * 8) = cvt8(s1c, s1d);
  };
  auto DMAW = [&](int buf, int kk) {
    gld_lds16(W + (size_t)(n0 + row0) * Dmodel + kk + ko0, (void*)(Bs[buf] + c0 * 8));
    gld_lds16(W + (size_t)(n0 + row1) * Dmodel + kk + ko1, (void*)(Bs[buf] + c1 * 8));
  };

  f32x4 zero = {0.f, 0.f, 0.f, 0.f};
  f32x4 acc[4][4];
#pragma unroll
  for (int mi = 0; mi < 4; ++mi)
#pragma unroll
    for (int ni = 0; ni < 4; ++ni) acc[mi][ni] = zero;

  auto COMPUTE = [&](const bf16* as, const bf16* bs) {
    bf16x8 af[4], bfr[4];
#pragma unroll
    for (int i = 0; i < 4; ++i) {
      af[i]  = *(const bf16x8*)(as + (wm + i * 16 + l15) * 32 + quad * 8);
      bfr[i] = *(const bf16x8*)(bs + (wn + i * 16 + l15) * 32 + quad * 8);
    }
#pragma unroll
    for (int mi = 0; mi < 4; ++mi)
#pragma unroll
      for (int ni = 0; ni < 4; ++ni)
        acc[mi][ni] = __builtin_amdgcn_mfma_f32_16x16x32_bf16(af[mi], bfr[ni],
                                                              acc[mi][ni], 0, 0, 0);
  };

  // prologue: tile0 staged (A via regs, W via DMA); tile1 A-loads in flight
  LOAD0(0);
  DMAW(0, 0);
  WRITE0(0);
  LOAD1(32);
  __syncthreads();

  for (int t = 0; t < 32; t += 2) {
    // even step: compute tile t from buf0
    if (t < 31) { DMAW(1, (t + 1) * 32); WRITE1(1); }   // tile t+1 -> buf1
    if (t < 30) LOAD0((t + 2) * 32);                    // issue tile t+2 loads
    COMPUTE(As[0], Bs[0]);
    __syncthreads();
    // odd step: compute tile t+1 from buf1
    if (t < 30) { DMAW(0, (t + 2) * 32); WRITE0(0); }   // tile t+2 -> buf0
    if (t < 29) LOAD1((t + 3) * 32);                    // issue tile t+3 loads
    COMPUTE(As[1], Bs[1]);
    __syncthreads();
  }

#pragma unroll
  for (int mi = 0; mi < 4; ++mi) {
#pragma unroll
    for (int r2 = 0; r2 < 4; ++r2) {
      const int m = m0 + wm + mi * 16 + quad * 4 + r2;
      const int bb = m >> 11, tt = m & 2047;
#pragma unroll
      for (int ni = 0; ni < 4; ++ni) {
        const int n = n0 + wn + ni * 16 + l15;
        const float val = (acc[mi][ni][r2] + bias[n]) * scl;
        bf16* o = (bf16*)g.out[z];
        const int hh = n >> 6, dk = n & 63;
        if (mode == 0) {
          o[((size_t)(bb * Hn + hh) * Tseq + tt) * DKd + dk] = (bf16)val;
        } else {
          o[((size_t)(bb * Hn + hh) * DKd + dk) * Tseq + tt] = (bf16)val;
        }
      }
    }
  }
}

// ---------------- out-projection GEMM, 64x128 tile, BK=32, dbuf 2-phase ------
__global__ void __launch_bounds__(256) gemm_out64(const bf16* __restrict__ A,
                                                  const bf16* __restrict__ W,
                                                  const float* __restrict__ bias,
                                                  float* __restrict__ out) {
  const int l = blockIdx.x;                // 512 blocks
  const int mt = (l & 7) * 8 + (l >> 6);   // [0,64)
  const int nt = (l >> 3) & 7;             // [0,8)

  __shared__ __align__(16) bf16 As[2][64 * 32];
  __shared__ __align__(16) bf16 Bs[2][128 * 32];

  const int tid = threadIdx.x;
  const int w = tid >> 6, lane = tid & 63;
  const int l15 = lane & 15, quad = lane >> 4;
  const int wm = (w >> 1) * 32, wn = (w & 1) * 64;
  const int m0 = mt * 64, n0 = nt * 128;

  const int c0 = tid, c1 = 256 + tid;
  const int rowA = c0 >> 2, koA = (c0 & 3) * 8;
  const int row0 = c0 >> 2, ko0 = (c0 & 3) * 8;
  const int row1 = c1 >> 2, ko1 = (c1 & 3) * 8;

  auto STAGE = [&](int buf, int k0) {
    gld_lds16(A + (size_t)(m0 + rowA) * Dmodel + k0 + koA, (void*)(As[buf] + c0 * 8));
    gld_lds16(W + (size_t)(n0 + row0) * Dmodel + k0 + ko0, (void*)(Bs[buf] + c0 * 8));
    gld_lds16(W + (size_t)(n0 + row1) * Dmodel + k0 + ko1, (void*)(Bs[buf] + c1 * 8));
  };

  f32x4 zero = {0.f, 0.f, 0.f, 0.f};
  f32x4 acc[2][4];
#pragma unroll
  for (int mi = 0; mi < 2; ++mi)
#pragma unroll
    for (int ni = 0; ni < 4; ++ni) acc[mi][ni] = zero;

  STAGE(0, 0);
  __syncthreads();

  for (int t = 0; t < 32; ++t) {
    const int cur = t & 1;
    if (t < 31) STAGE(cur ^ 1, (t + 1) * 32);

    bf16x8 af[2], bfr[4];
#pragma unroll
    for (int i = 0; i < 2; ++i)
      af[i] = *(const bf16x8*)(As[cur] + (wm + i * 16 + l15) * 32 + quad * 8);
#pragma unroll
    for (int i = 0; i < 4; ++i)
      bfr[i] = *(const bf16x8*)(Bs[cur] + (wn + i * 16 + l15) * 32 + quad * 8);
#pragma unroll
    for (int mi = 0; mi < 2; ++mi)
#pragma unroll
      for (int ni = 0; ni < 4; ++ni)
        acc[mi][ni] = __builtin_amdgcn_mfma_f32_16x16x32_bf16(af[mi], bfr[ni],
                                                              acc[mi][ni], 0, 0, 0);
    __syncthreads();
  }

#pragma unroll
  for (int mi = 0; mi < 2; ++mi)
#pragma unroll
    for (int r = 0; r < 4; ++r) {
      const int m = m0 + wm + mi * 16 + quad * 4 + r;
#pragma unroll
      for (int ni = 0; ni < 4; ++ni) {
        const int n = n0 + wn + ni * 16 + l15;
        out[(size_t)m * Dmodel + n] = acc[mi][ni][r] + bias[n];
      }
    }
}

// ---------------- fused causal attention (transposed-S) ----------------------
// Round-5: round-2 staged-K/V structure, but 64-key tiles double-buffered:
// stage(next tile) is issued BEFORE compute(cur), so the loop-top
// __syncthreads drain waits on DMAs issued one full tile of compute earlier.
// LDS: Ks[2] 16 KB + Vs[2] 16 KB + plds (pad 68) 8.7 KB = 40.7 KB -> 4
// blocks/CU (was 3). Diagonal handling identical at 64-key granularity with
// statically-indexed PV (rule #20).
__global__ void __launch_bounds__(256) attn_fused(const bf16* __restrict__ Q,
                                                  const bf16* __restrict__ K,
                                                  const bf16* __restrict__ Vt,
                                                  bf16* __restrict__ ctx) {
  __shared__ __align__(16) bf16 Ks[2][8 * 64 * 8];  // [dk-chunk][row][8] 8 KB/buf
  __shared__ __align__(16) bf16 Vs[2][8 * 64 * 8];  // [key-chunk][d][8]  8 KB/buf
  __shared__ __align__(16) bf16 plds[4][16][68];    // per-wave P, pad 4 -> 8.7 KB

  const int tid = threadIdx.x;
  const int w = tid >> 6, lane = tid & 63;
  const int l15 = lane & 15, quad = lane >> 4;

  // longest-first: qt descending outer, (h,b) inner (stride 32 -> same XCD)
  const int l = blockIdx.x;                 // 1024 blocks
  const int qt = (Tseq / 64 - 1) - (l >> 5);
  const int hb = l & 31;
  const int h = hb & 15, b = hb >> 4;
  const int bh = b * Hn + h;
  const int qb = qt * 64 + w * 16;

  const bf16* Qb = Q + (size_t)bh * Tseq * DKd;
  const bf16* Kb = K + (size_t)bh * Tseq * DKd;
  const bf16* Vb = Vt + (size_t)bh * DKd * Tseq;

  auto STAGE = [&](int buf, int j0n) {
#pragma unroll
    for (int p = 0; p < 2; ++p) {
      const int c = p * 256 + tid;          // 0..511
      const int rr = c & 63, ch = c >> 6;   // row/d, 8-elem chunk
      gld_lds16(Kb + (size_t)(j0n + rr) * DKd + ch * 8, (void*)(Ks[buf] + c * 8));
      gld_lds16(Vb + (size_t)rr * Tseq + j0n + ch * 8, (void*)(Vs[buf] + c * 8));
    }
  };

  // Q fragment, B-operand role: n=l15 -> q-row, k=quad*8+j -> dk
  bf16x8 aq0 = *(const bf16x8*)(Qb + (size_t)(qb + l15) * DKd + quad * 8);
  bf16x8 aq1 = *(const bf16x8*)(Qb + (size_t)(qb + l15) * DKd + 32 + quad * 8);

  f32x4 zero = {0.f, 0.f, 0.f, 0.f};
  f32x4 oacc[4];
#pragma unroll
  for (int nd = 0; nd < 4; ++nd) oacc[nd] = zero;
  f32x4 lacc = zero;

  bf16x8 onesf;
#pragma unroll
  for (int i = 0; i < 8; ++i) onesf[i] = (bf16)1.0f;

  const int qmax = qt * 64 + 48;  // last tile start (step 64 lands on qt*64)
  STAGE(0, 0);
  int cur = 0;

  for (int j0 = 0; j0 <= qmax; j0 += 64) {
    __syncthreads();  // [cur] DMA landed; prior tile's reads done
    if (j0 + 64 <= qmax) STAGE(cur ^ 1, j0 + 64);  // in flight across compute

    const bf16* ks = Ks[cur];
    const bf16* vs = Vs[cur];

    if (j0 + 64 <= qb) {
      // ---------- fully unmasked tile ----------
      f32x4 s[4];
#pragma unroll
      for (int ct = 0; ct < 4; ++ct) s[ct] = zero;
#pragma unroll
      for (int ct = 0; ct < 4; ++ct) {
        bf16x8 bk0 = *(const bf16x8*)(ks + ((quad)*64 + ct * 16 + l15) * 8);
        bf16x8 bk1 = *(const bf16x8*)(ks + ((4 + quad) * 64 + ct * 16 + l15) * 8);
        s[ct] = __builtin_amdgcn_mfma_f32_16x16x32_bf16(bk0, aq0, s[ct], 0, 0, 0);
        s[ct] = __builtin_amdgcn_mfma_f32_16x16x32_bf16(bk1, aq1, s[ct], 0, 0, 0);
      }
#pragma unroll
      for (int ct = 0; ct < 4; ++ct)
        pack4_store(&plds[w][l15][ct * 16 + quad * 4],
                    exp2f(s[ct][0]), exp2f(s[ct][1]),
                    exp2f(s[ct][2]), exp2f(s[ct][3]));
#pragma unroll
      for (int kc = 0; kc < 2; ++kc) {
        bf16x8 bp = *(const bf16x8*)(&plds[w][l15][kc * 32 + quad * 8]);
        lacc = __builtin_amdgcn_mfma_f32_16x16x32_bf16(onesf, bp, lacc, 0, 0, 0);
#pragma unroll
        for (int nd = 0; nd < 4; ++nd) {
          bf16x8 bv = *(const bf16x8*)(vs + ((kc * 4 + quad) * 64 + nd * 16 + l15) * 8);
          oacc[nd] = __builtin_amdgcn_mfma_f32_16x16x32_bf16(bv, bp, oacc[nd], 0, 0, 0);
        }
      }
    } else if (j0 <= qb) {
      // ---------- diagonal tile: only live column-tiles (wave-uniform) -------
      const int ctl = ((qb - j0) >> 4) + 1;     // 1..4 live 16-col tiles
      const int kclim = (ctl + 1) >> 1;         // 1..2 live 32-col PV chunks
      for (int ct = 0; ct < ctl; ++ct) {
        bf16x8 bk0 = *(const bf16x8*)(ks + ((quad)*64 + ct * 16 + l15) * 8);
        bf16x8 bk1 = *(const bf16x8*)(ks + ((4 + quad) * 64 + ct * 16 + l15) * 8);
        f32x4 s = zero;
        s = __builtin_amdgcn_mfma_f32_16x16x32_bf16(bk0, aq0, s, 0, 0, 0);
        s = __builtin_amdgcn_mfma_f32_16x16x32_bf16(bk1, aq1, s, 0, 0, 0);
        float p[4];
#pragma unroll
        for (int r = 0; r < 4; ++r) {
          p[r] = exp2f(s[r]);
          // mask only possible in the last live tile: key > qrow
          if (ct == ctl - 1 && (j0 + ct * 16 + quad * 4 + r > qb + l15)) p[r] = 0.f;
        }
        pack4_store(&plds[w][l15][ct * 16 + quad * 4], p[0], p[1], p[2], p[3]);
      }
      if (ctl < 4)  // zero the 16-col block the last b128 P-read may touch
        pack4_store(&plds[w][l15][ctl * 16 + quad * 4], 0.f, 0.f, 0.f, 0.f);
      // static kc indexing, wave-uniform guard (rule #20)
#pragma unroll
      for (int kc = 0; kc < 2; ++kc) {
        if (kc < kclim) {
          bf16x8 bp = *(const bf16x8*)(&plds[w][l15][kc * 32 + quad * 8]);
          lacc = __builtin_amdgcn_mfma_f32_16x16x32_bf16(onesf, bp, lacc, 0, 0, 0);
#pragma unroll
          for (int nd = 0; nd < 4; ++nd) {
            bf16x8 bv = *(const bf16x8*)(vs + ((kc * 4 + quad) * 64 + nd * 16 + l15) * 8);
            oacc[nd] = __builtin_amdgcn_mfma_f32_16x16x32_bf16(bv, bp, oacc[nd], 0, 0, 0);
          }
        }
      }
    }
    cur ^= 1;
  }

  // epilogue: O^T lane layout = q-row l15, d = quad*4 + r (packed b64 stores)
  const float inv = 1.0f / lacc[0];
  bf16* cb = ctx + (size_t)(b * Tseq + qb + l15) * Dmodel + h * DKd + quad * 4;
#pragma unroll
  for (int nd = 0; nd < 4; ++nd)
    pack4_store(cb + nd * 16, oacc[nd][0] * inv, oacc[nd][1] * inv,
                oacc[nd][2] * inv, oacc[nd][3] * inv);
}

// -------------------------------- launcher ------------------------------------
extern "C" void kernel_launch(void* const* d_in, const int* in_sizes, int n_in,
                              void* d_out, int out_size, void* d_ws, size_t ws_size,
                              hipStream_t stream) {
  const float* q = (const float*)d_in[0];
  const float* k = (const float*)d_in[1];
  const float* v = (const float*)d_in[2];
  // d_in[3] = attn_mask (causal, known statically) - unused
  const float* Wq = (const float*)d_in[4];
  const float* bq = (const float*)d_in[5];
  const float* Wk = (const float*)d_in[6];
  const float* bk = (const float*)d_in[7];
  const float* Wv = (const float*)d_in[8];
  const float* bv = (const float*)d_in[9];
  const float* Wo = (const float*)d_in[10];
  const float* bo = (const float*)d_in[11];

  char* ws = (char*)d_ws;
  const size_t MB = 1024 * 1024;
  bf16* Wq_b = (bf16*)(ws + 0 * MB);
  bf16* Wk_b = (bf16*)(ws + 2 * MB);
  bf16* Wv_b = (bf16*)(ws + 4 * MB);
  bf16* Wo_b = (bf16*)(ws + 6 * MB);
  bf16* ctx  = (bf16*)(ws + 8 * MB);
  bf16* Qh   = (bf16*)(ws + 32 * MB);  // [B,H,T,DK], pre-scaled
  bf16* Kh   = (bf16*)(ws + 40 * MB);  // [B,H,T,DK]
  bf16* Vt   = (bf16*)(ws + 48 * MB);  // [B,H,DK,T]

  const int NW4 = (Dmodel * Dmodel) / 4;

  CvtArgs ca;
  ca.src[0] = Wq; ca.dst[0] = Wq_b; ca.n4[0] = NW4;
  ca.src[1] = Wk; ca.dst[1] = Wk_b; ca.n4[1] = NW4;
  ca.src[2] = Wv; ca.dst[2] = Wv_b; ca.n4[2] = NW4;
  ca.src[3] = Wo; ca.dst[3] = Wo_b; ca.n4[3] = NW4;
  cvt_f32_bf16<<<dim3(128, 4), 256, 0, stream>>>(ca);

  const float SC = 0.125f * 1.4426950408889634f;  // 1/sqrt(DK) * log2(e)
  GemmArgs ga;
  ga.A[0] = q; ga.W[0] = Wq_b; ga.bias[0] = bq; ga.out[0] = Qh; ga.mode[0] = 0; ga.scale[0] = SC;
  ga.A[1] = k; ga.W[1] = Wk_b; ga.bias[1] = bk; ga.out[1] = Kh; ga.mode[1] = 0; ga.scale[1] = 1.f;
  ga.A[2] = v; ga.W[2] = Wv_b; ga.bias[2] = bv; ga.out[2] = Vt; ga.mode[2] = 1; ga.scale[2] = 1.f;
  gemm_qkv<<<dim3(768), 256, 0, stream>>>(ga);

  attn_fused<<<dim3((Tseq / 64) * Hn * Bsz), 256, 0, stream>>>(Qh, Kh, Vt, ctx);

  gemm_out64<<<dim3(512), 256, 0, stream>>>(ctx, Wo_b, bo, (float*)d_out);
}

// Round 7
// 239.911 us; speedup vs baseline: 1.4178x; 1.1387x over previous
//
#include <hip/hip_runtime.h>
#include <stdint.h>

#define Bsz 2
#define Tseq 2048
#define Dmodel 1024
#define Hn 16
#define DKd 64

typedef __bf16 bf16;
typedef bf16 bf16x8 __attribute__((ext_vector_type(8)));
typedef float f32x4 __attribute__((ext_vector_type(4)));

// async global->LDS, 16B per lane. LDS dest must be wave-uniform base + lane*16
// and contiguous across the wave's lanes (no padding on DMA'd tiles).
__device__ inline void gld_lds16(const void* g, void* l) {
  __builtin_amdgcn_global_load_lds(
      (const __attribute__((address_space(1))) uint32_t*)g,
      (__attribute__((address_space(3))) uint32_t*)l, 16, 0, 0);
}

// pack 4 fp32 -> 4 bf16, single 8B store
__device__ inline void pack4_store(bf16* dst, float a, float b, float c, float d) {
  union { bf16 h[4]; uint2 u; } pk;
  pk.h[0] = (bf16)a; pk.h[1] = (bf16)b; pk.h[2] = (bf16)c; pk.h[3] = (bf16)d;
  *(uint2*)dst = pk.u;
}

// ---------------- fp32 -> bf16 convert (activations + weights) ----------------
struct CvtArgs {
  const float* src[7];
  bf16* dst[7];
  int n4[7];
};

__global__ void __launch_bounds__(256) cvt_f32_bf16(CvtArgs a) {
  const int z = blockIdx.y;
  const float4* s = (const float4*)a.src[z];
  uint2* d = (uint2*)a.dst[z];
  const int n4 = a.n4[z];
  for (int i = blockIdx.x * 256 + threadIdx.x; i < n4; i += gridDim.x * 256) {
    float4 v = s[i];
    union { bf16 h[4]; uint2 u; } pk;
    pk.h[0] = (bf16)v.x; pk.h[1] = (bf16)v.y;
    pk.h[2] = (bf16)v.z; pk.h[3] = (bf16)v.w;
    d[i] = pk.u;
  }
}

// ---------------- QKV GEMM: C = (A * W^T + bias)*scale, bf16 in --------------
// 128x128 tile, BK=32, XCD-swizzled 1D grid. T3 minimum-2-phase double buffer:
// stage(next K-tile) issued BEFORE compute(cur); the __syncthreads() drain at
// iteration end waits on loads issued one full compute phase earlier.
// LDS 32 KB (2x dbuf), 768 blocks -> 3 blocks/CU.  [round-2 proven: <50 us]
// mode 0: bf16 [B,H,T,DK]; mode 1: bf16 [B,H,DK,T].
struct GemmArgs {
  const bf16* A[3];
  const bf16* W[3];
  const float* bias[3];
  void* out[3];
  int mode[3];
  float scale[3];
};

__global__ void __launch_bounds__(256) gemm_qkv(GemmArgs g) {
  const int l = blockIdx.x;
  const int z = l >> 8;           // 768 = 3 * 256
  const int r = l & 255;
  const int mt = (r & 7) * 4 + (r >> 6);  // [0,32)
  const int nt = (r >> 3) & 7;            // [0,8)
  const bf16* __restrict__ A = g.A[z];
  const bf16* __restrict__ W = g.W[z];
  const float* __restrict__ bias = g.bias[z];
  const int mode = g.mode[z];
  const float scl = g.scale[z];

  __shared__ __align__(16) bf16 As[2][128 * 32];
  __shared__ __align__(16) bf16 Bs[2][128 * 32];

  const int tid = threadIdx.x;
  const int w = tid >> 6, lane = tid & 63;
  const int l15 = lane & 15, quad = lane >> 4;
  const int wm = (w >> 1) * 64, wn = (w & 1) * 64;
  const int m0 = mt * 128, n0 = nt * 128;

  // per-thread staging coords (2 chunks per buffer side)
  const int c0 = tid, c1 = 256 + tid;
  const int row0 = c0 >> 2, ko0 = (c0 & 3) * 8;
  const int row1 = c1 >> 2, ko1 = (c1 & 3) * 8;

  auto STAGE = [&](int buf, int k0) {
    gld_lds16(A + (size_t)(m0 + row0) * Dmodel + k0 + ko0, (void*)(As[buf] + c0 * 8));
    gld_lds16(W + (size_t)(n0 + row0) * Dmodel + k0 + ko0, (void*)(Bs[buf] + c0 * 8));
    gld_lds16(A + (size_t)(m0 + row1) * Dmodel + k0 + ko1, (void*)(As[buf] + c1 * 8));
    gld_lds16(W + (size_t)(n0 + row1) * Dmodel + k0 + ko1, (void*)(Bs[buf] + c1 * 8));
  };

  f32x4 zero = {0.f, 0.f, 0.f, 0.f};
  f32x4 acc[4][4];
#pragma unroll
  for (int mi = 0; mi < 4; ++mi)
#pragma unroll
    for (int ni = 0; ni < 4; ++ni) acc[mi][ni] = zero;

  STAGE(0, 0);
  __syncthreads();

  for (int t = 0; t < 32; ++t) {
    const int cur = t & 1;
    if (t < 31) STAGE(cur ^ 1, (t + 1) * 32);  // prefetch next K-tile

    bf16x8 af[4], bfr[4];
#pragma unroll
    for (int i = 0; i < 4; ++i) {
      af[i]  = *(const bf16x8*)(As[cur] + (wm + i * 16 + l15) * 32 + quad * 8);
      bfr[i] = *(const bf16x8*)(Bs[cur] + (wn + i * 16 + l15) * 32 + quad * 8);
    }
#pragma unroll
    for (int mi = 0; mi < 4; ++mi)
#pragma unroll
      for (int ni = 0; ni < 4; ++ni)
        acc[mi][ni] = __builtin_amdgcn_mfma_f32_16x16x32_bf16(af[mi], bfr[ni],
                                                              acc[mi][ni], 0, 0, 0);
    __syncthreads();  // drains vmcnt(0): next buffer landed; all reads done
  }

#pragma unroll
  for (int mi = 0; mi < 4; ++mi) {
#pragma unroll
    for (int r2 = 0; r2 < 4; ++r2) {
      const int m = m0 + wm + mi * 16 + quad * 4 + r2;
      const int bb = m >> 11, tt = m & 2047;
#pragma unroll
      for (int ni = 0; ni < 4; ++ni) {
        const int n = n0 + wn + ni * 16 + l15;
        const float val = (acc[mi][ni][r2] + bias[n]) * scl;
        bf16* o = (bf16*)g.out[z];
        const int hh = n >> 6, dk = n & 63;
        if (mode == 0) {
          o[((size_t)(bb * Hn + hh) * Tseq + tt) * DKd + dk] = (bf16)val;
        } else {
          o[((size_t)(bb * Hn + hh) * DKd + dk) * Tseq + tt] = (bf16)val;
        }
      }
    }
  }
}

// ---------------- out-projection GEMM, 64x128 tile, BK=32, dbuf 2-phase ------
__global__ void __launch_bounds__(256) gemm_out64(const bf16* __restrict__ A,
                                                  const bf16* __restrict__ W,
                                                  const float* __restrict__ bias,
                                                  float* __restrict__ out) {
  const int l = blockIdx.x;                // 512 blocks
  const int mt = (l & 7) * 8 + (l >> 6);   // [0,64)
  const int nt = (l >> 3) & 7;             // [0,8)

  __shared__ __align__(16) bf16 As[2][64 * 32];
  __shared__ __align__(16) bf16 Bs[2][128 * 32];

  const int tid = threadIdx.x;
  const int w = tid >> 6, lane = tid & 63;
  const int l15 = lane & 15, quad = lane >> 4;
  const int wm = (w >> 1) * 32, wn = (w & 1) * 64;
  const int m0 = mt * 64, n0 = nt * 128;

  const int c0 = tid, c1 = 256 + tid;
  const int rowA = c0 >> 2, koA = (c0 & 3) * 8;
  const int row0 = c0 >> 2, ko0 = (c0 & 3) * 8;
  const int row1 = c1 >> 2, ko1 = (c1 & 3) * 8;

  auto STAGE = [&](int buf, int k0) {
    gld_lds16(A + (size_t)(m0 + rowA) * Dmodel + k0 + koA, (void*)(As[buf] + c0 * 8));
    gld_lds16(W + (size_t)(n0 + row0) * Dmodel + k0 + ko0, (void*)(Bs[buf] + c0 * 8));
    gld_lds16(W + (size_t)(n0 + row1) * Dmodel + k0 + ko1, (void*)(Bs[buf] + c1 * 8));
  };

  f32x4 zero = {0.f, 0.f, 0.f, 0.f};
  f32x4 acc[2][4];
#pragma unroll
  for (int mi = 0; mi < 2; ++mi)
#pragma unroll
    for (int ni = 0; ni < 4; ++ni) acc[mi][ni] = zero;

  STAGE(0, 0);
  __syncthreads();

  for (int t = 0; t < 32; ++t) {
    const int cur = t & 1;
    if (t < 31) STAGE(cur ^ 1, (t + 1) * 32);

    bf16x8 af[2], bfr[4];
#pragma unroll
    for (int i = 0; i < 2; ++i)
      af[i] = *(const bf16x8*)(As[cur] + (wm + i * 16 + l15) * 32 + quad * 8);
#pragma unroll
    for (int i = 0; i < 4; ++i)
      bfr[i] = *(const bf16x8*)(Bs[cur] + (wn + i * 16 + l15) * 32 + quad * 8);
#pragma unroll
    for (int mi = 0; mi < 2; ++mi)
#pragma unroll
      for (int ni = 0; ni < 4; ++ni)
        acc[mi][ni] = __builtin_amdgcn_mfma_f32_16x16x32_bf16(af[mi], bfr[ni],
                                                              acc[mi][ni], 0, 0, 0);
    __syncthreads();
  }

#pragma unroll
  for (int mi = 0; mi < 2; ++mi)
#pragma unroll
    for (int r = 0; r < 4; ++r) {
      const int m = m0 + wm + mi * 16 + quad * 4 + r;
#pragma unroll
      for (int ni = 0; ni < 4; ++ni) {
        const int n = n0 + wn + ni * 16 + l15;
        out[(size_t)m * Dmodel + n] = acc[mi][ni][r] + bias[n];
      }
    }
}

// ---------------- fused causal attention (transposed-S) ----------------------
// Round-5 structure (kept): staged K/V, 64-key tiles double-buffered:
// stage(next tile) issued BEFORE compute(cur); loop-top __syncthreads drain
// waits on DMAs issued one full tile of compute earlier.
// LDS: Ks[2] 16 KB + Vs[2] 16 KB + plds (pad 68) 8.7 KB = 40.7 KB -> 4
// blocks/CU. Diagonal tiles: statically-indexed PV (rule #20).
__global__ void __launch_bounds__(256) attn_fused(const bf16* __restrict__ Q,
                                                  const bf16* __restrict__ K,
                                                  const bf16* __restrict__ Vt,
                                                  bf16* __restrict__ ctx) {
  __shared__ __align__(16) bf16 Ks[2][8 * 64 * 8];  // [dk-chunk][row][8] 8 KB/buf
  __shared__ __align__(16) bf16 Vs[2][8 * 64 * 8];  // [key-chunk][d][8]  8 KB/buf
  __shared__ __align__(16) bf16 plds[4][16][68];    // per-wave P, pad 4 -> 8.7 KB

  const int tid = threadIdx.x;
  const int w = tid >> 6, lane = tid & 63;
  const int l15 = lane & 15, quad = lane >> 4;

  // longest-first: qt descending outer, (h,b) inner (stride 32 -> same XCD)
  const int l = blockIdx.x;                 // 1024 blocks
  const int qt = (Tseq / 64 - 1) - (l >> 5);
  const int hb = l & 31;
  const int h = hb & 15, b = hb >> 4;
  const int bh = b * Hn + h;
  const int qb = qt * 64 + w * 16;

  const bf16* Qb = Q + (size_t)bh * Tseq * DKd;
  const bf16* Kb = K + (size_t)bh * Tseq * DKd;
  const bf16* Vb = Vt + (size_t)bh * DKd * Tseq;

  auto STAGE = [&](int buf, int j0n) {
#pragma unroll
    for (int p = 0; p < 2; ++p) {
      const int c = p * 256 + tid;          // 0..511
      const int rr = c & 63, ch = c >> 6;   // row/d, 8-elem chunk
      gld_lds16(Kb + (size_t)(j0n + rr) * DKd + ch * 8, (void*)(Ks[buf] + c * 8));
      gld_lds16(Vb + (size_t)rr * Tseq + j0n + ch * 8, (void*)(Vs[buf] + c * 8));
    }
  };

  // Q fragment, B-operand role: n=l15 -> q-row, k=quad*8+j -> dk
  bf16x8 aq0 = *(const bf16x8*)(Qb + (size_t)(qb + l15) * DKd + quad * 8);
  bf16x8 aq1 = *(const bf16x8*)(Qb + (size_t)(qb + l15) * DKd + 32 + quad * 8);

  f32x4 zero = {0.f, 0.f, 0.f, 0.f};
  f32x4 oacc[4];
#pragma unroll
  for (int nd = 0; nd < 4; ++nd) oacc[nd] = zero;
  f32x4 lacc = zero;

  bf16x8 onesf;
#pragma unroll
  for (int i = 0; i < 8; ++i) onesf[i] = (bf16)1.0f;

  const int qmax = qt * 64 + 48;  // last tile start
  STAGE(0, 0);
  int cur = 0;

  for (int j0 = 0; j0 <= qmax; j0 += 64) {
    __syncthreads();  // [cur] DMA landed; prior tile's reads done
    if (j0 + 64 <= qmax) STAGE(cur ^ 1, j0 + 64);  // in flight across compute

    const bf16* ks = Ks[cur];
    const bf16* vs = Vs[cur];

    if (j0 + 64 <= qb) {
      // ---------- fully unmasked tile ----------
      f32x4 s[4];
#pragma unroll
      for (int ct = 0; ct < 4; ++ct) s[ct] = zero;
#pragma unroll
      for (int ct = 0; ct < 4; ++ct) {
        bf16x8 bk0 = *(const bf16x8*)(ks + ((quad)*64 + ct * 16 + l15) * 8);
        bf16x8 bk1 = *(const bf16x8*)(ks + ((4 + quad) * 64 + ct * 16 + l15) * 8);
        s[ct] = __builtin_amdgcn_mfma_f32_16x16x32_bf16(bk0, aq0, s[ct], 0, 0, 0);
        s[ct] = __builtin_amdgcn_mfma_f32_16x16x32_bf16(bk1, aq1, s[ct], 0, 0, 0);
      }
#pragma unroll
      for (int ct = 0; ct < 4; ++ct)
        pack4_store(&plds[w][l15][ct * 16 + quad * 4],
                    exp2f(s[ct][0]), exp2f(s[ct][1]),
                    exp2f(s[ct][2]), exp2f(s[ct][3]));
#pragma unroll
      for (int kc = 0; kc < 2; ++kc) {
        bf16x8 bp = *(const bf16x8*)(&plds[w][l15][kc * 32 + quad * 8]);
        lacc = __builtin_amdgcn_mfma_f32_16x16x32_bf16(onesf, bp, lacc, 0, 0, 0);
#pragma unroll
        for (int nd = 0; nd < 4; ++nd) {
          bf16x8 bv = *(const bf16x8*)(vs + ((kc * 4 + quad) * 64 + nd * 16 + l15) * 8);
          oacc[nd] = __builtin_amdgcn_mfma_f32_16x16x32_bf16(bv, bp, oacc[nd], 0, 0, 0);
        }
      }
    } else if (j0 <= qb) {
      // ---------- diagonal tile: only live column-tiles (wave-uniform) -------
      const int ctl = ((qb - j0) >> 4) + 1;     // 1..4 live 16-col tiles
      const int kclim = (ctl + 1) >> 1;         // 1..2 live 32-col PV chunks
      for (int ct = 0; ct < ctl; ++ct) {
        bf16x8 bk0 = *(const bf16x8*)(ks + ((quad)*64 + ct * 16 + l15) * 8);
        bf16x8 bk1 = *(const bf16x8*)(ks + ((4 + quad) * 64 + ct * 16 + l15) * 8);
        f32x4 s = zero;
        s = __builtin_amdgcn_mfma_f32_16x16x32_bf16(bk0, aq0, s, 0, 0, 0);
        s = __builtin_amdgcn_mfma_f32_16x16x32_bf16(bk1, aq1, s, 0, 0, 0);
        float p[4];
#pragma unroll
        for (int r = 0; r < 4; ++r) {
          p[r] = exp2f(s[r]);
          // mask only possible in the last live tile: key > qrow
          if (ct == ctl - 1 && (j0 + ct * 16 + quad * 4 + r > qb + l15)) p[r] = 0.f;
        }
        pack4_store(&plds[w][l15][ct * 16 + quad * 4], p[0], p[1], p[2], p[3]);
      }
      if (ctl < 4)  // zero the 16-col block the last b128 P-read may touch
        pack4_store(&plds[w][l15][ctl * 16 + quad * 4], 0.f, 0.f, 0.f, 0.f);
      // static kc indexing, wave-uniform guard (rule #20)
#pragma unroll
      for (int kc = 0; kc < 2; ++kc) {
        if (kc < kclim) {
          bf16x8 bp = *(const bf16x8*)(&plds[w][l15][kc * 32 + quad * 8]);
          lacc = __builtin_amdgcn_mfma_f32_16x16x32_bf16(onesf, bp, lacc, 0, 0, 0);
#pragma unroll
          for (int nd = 0; nd < 4; ++nd) {
            bf16x8 bv = *(const bf16x8*)(vs + ((kc * 4 + quad) * 64 + nd * 16 + l15) * 8);
            oacc[nd] = __builtin_amdgcn_mfma_f32_16x16x32_bf16(bv, bp, oacc[nd], 0, 0, 0);
          }
        }
      }
    }
    cur ^= 1;
  }

  // epilogue: O^T lane layout = q-row l15, d = quad*4 + r (packed b64 stores)
  const float inv = 1.0f / lacc[0];
  bf16* cb = ctx + (size_t)(b * Tseq + qb + l15) * Dmodel + h * DKd + quad * 4;
#pragma unroll
  for (int nd = 0; nd < 4; ++nd)
    pack4_store(cb + nd * 16, oacc[nd][0] * inv, oacc[nd][1] * inv,
                oacc[nd][2] * inv, oacc[nd][3] * inv);
}

// -------------------------------- launcher ------------------------------------
extern "C" void kernel_launch(void* const* d_in, const int* in_sizes, int n_in,
                              void* d_out, int out_size, void* d_ws, size_t ws_size,
                              hipStream_t stream) {
  const float* q = (const float*)d_in[0];
  const float* k = (const float*)d_in[1];
  const float* v = (const float*)d_in[2];
  // d_in[3] = attn_mask (causal, known statically) - unused
  const float* Wq = (const float*)d_in[4];
  const float* bq = (const float*)d_in[5];
  const float* Wk = (const float*)d_in[6];
  const float* bk = (const float*)d_in[7];
  const float* Wv = (const float*)d_in[8];
  const float* bv = (const float*)d_in[9];
  const float* Wo = (const float*)d_in[10];
  const float* bo = (const float*)d_in[11];

  char* ws = (char*)d_ws;
  const size_t MB = 1024 * 1024;
  bf16* Wq_b = (bf16*)(ws + 0 * MB);
  bf16* Wk_b = (bf16*)(ws + 2 * MB);
  bf16* Wv_b = (bf16*)(ws + 4 * MB);
  bf16* Wo_b = (bf16*)(ws + 6 * MB);
  bf16* q_b  = (bf16*)(ws + 8 * MB);   // dead after QKV gemm
  bf16* k_b  = (bf16*)(ws + 16 * MB);
  bf16* v_b  = (bf16*)(ws + 24 * MB);
  bf16* Qh   = (bf16*)(ws + 32 * MB);  // [B,H,T,DK], pre-scaled
  bf16* Kh   = (bf16*)(ws + 40 * MB);  // [B,H,T,DK]
  bf16* Vt   = (bf16*)(ws + 48 * MB);  // [B,H,DK,T]
  bf16* ctx  = (bf16*)(ws + 8 * MB);   // aliases q_b (dead by then)

  const int NACT4 = (Bsz * Tseq * Dmodel) / 4;
  const int NW4 = (Dmodel * Dmodel) / 4;

  CvtArgs ca;
  ca.src[0] = q;  ca.dst[0] = q_b;  ca.n4[0] = NACT4;
  ca.src[1] = k;  ca.dst[1] = k_b;  ca.n4[1] = NACT4;
  ca.src[2] = v;  ca.dst[2] = v_b;  ca.n4[2] = NACT4;
  ca.src[3] = Wq; ca.dst[3] = Wq_b; ca.n4[3] = NW4;
  ca.src[4] = Wk; ca.dst[4] = Wk_b; ca.n4[4] = NW4;
  ca.src[5] = Wv; ca.dst[5] = Wv_b; ca.n4[5] = NW4;
  ca.src[6] = Wo; ca.dst[6] = Wo_b; ca.n4[6] = NW4;
  cvt_f32_bf16<<<dim3(512, 7), 256, 0, stream>>>(ca);

  const float SC = 0.125f * 1.4426950408889634f;  // 1/sqrt(DK) * log2(e)
  GemmArgs ga;
  ga.A[0] = q_b; ga.W[0] = Wq_b; ga.bias[0] = bq; ga.out[0] = Qh; ga.mode[0] = 0; ga.scale[0] = SC;
  ga.A[1] = k_b; ga.W[1] = Wk_b; ga.bias[1] = bk; ga.out[1] = Kh; ga.mode[1] = 0; ga.scale[1] = 1.f;
  ga.A[2] = v_b; ga.W[2] = Wv_b; ga.bias[2] = bv; ga.out[2] = Vt; ga.mode[2] = 1; ga.scale[2] = 1.f;
  gemm_qkv<<<dim3(768), 256, 0, stream>>>(ga);

  attn_fused<<<dim3((Tseq / 64) * Hn * Bsz), 256, 0, stream>>>(Qh, Kh, Vt, ctx);

  gemm_out64<<<dim3(512), 256, 0, stream>>>(ctx, Wo_b, bo, (float*)d_out);
}